// Round 6
// baseline (533.471 us; speedup 1.0000x reference)
//
#include <hip/hip_runtime.h>

// GCN 3-layer: out = GCNconv3(relu(GCNconv2(relu(GCNconv1(x)))))
//
// R16 = R15 agg/GEMM (267us) + direct per-dst counting-sort binning.
// Evidence R10-R15: agg is at the per-CU MSHR floor for random line fills
// (~7.3 cyc/line, 2 lines/edge, bf16 min precision) -> ~38us/layer floor.
// Remaining mass is the prologue: old 4-kernel chain moved the 12.8MB edge
// payload 3x (tile LDS sort -> binned -> LDS counting sort -> binned) and
// bin_group's 74KB LDS capped occupancy at 2 blocks/CU (196 blocks).
// R16 chain (one payload pass, no LDS sorts):
//   Z.  zero cnt/deg (50K each)
//   C.  count: atomicAdd(cnt[d],1), atomicAdd(deg[d],ew) -- 50K addresses,
//       avg 32 hits each, widely spread (unlike old 256-cursor serialization)
//   S.  scan: 1-block exclusive scan of cnt (region order arbitrary; only
//       per-d contiguity matters) -> row_start, run cursors, dinv
//   X.  scatter: pos = atomicAdd(run[d],1); binned[pos] = {src*128, ew}
// Edge order within a row is nondeterministic -> fp32 sum reorder only.
//
//   GEMM: per layer fp32 -> bf16 Y[r, stride 64] = dinv[r]*(X@W)[r]
//   agg (R15): 8 edges/VMEM gather via dwordx4, bpermute distribution,
//       out = dinv[d]*(sum_e ew*Y[s] + Y[d]) + b

static __device__ __forceinline__ float4 f4zero() { return make_float4(0.f, 0.f, 0.f, 0.f); }

static __device__ __forceinline__ unsigned short f2bf_rne(float x) {
    unsigned u = __float_as_uint(x);
    u += 0x7FFFu + ((u >> 16) & 1u);     // round-to-nearest-even
    return (unsigned short)(u >> 16);
}
static __device__ __forceinline__ float bflo(unsigned u) { return __uint_as_float(u << 16); }
static __device__ __forceinline__ float bfhi(unsigned u) { return __uint_as_float(u & 0xffff0000u); }

// ---------------- Z: zero counters ----------------------------------------
__global__ __launch_bounds__(1024) void zero_kernel(int* __restrict__ cnt,
        float* __restrict__ deg, int N) {
    int i = blockIdx.x * 1024 + threadIdx.x;
    if (i < N) { cnt[i] = 0; deg[i] = 0.f; }
}

// ---------------- C: per-dst histogram + degree ----------------------------
__global__ __launch_bounds__(1024) void count_kernel(
        const int* __restrict__ dst, const float* __restrict__ ew,
        int* __restrict__ cnt, float* __restrict__ deg, int E) {
    int stride = gridDim.x * 1024;
    for (int e = blockIdx.x * 1024 + threadIdx.x; e < E; e += stride) {
        int d = dst[e];
        atomicAdd(&cnt[d], 1);
        atomicAdd(&deg[d], ew[e]);
    }
}

// ---------------- S: single-block exclusive scan + dinv --------------------
// Thread t owns elements {i*1024+t}; regions assigned in that enumeration
// order (arbitrary but consistent). Writes row_start, run(=row_start), dinv.
__global__ __launch_bounds__(1024) void scan_kernel(
        const int* __restrict__ cnt, const float* __restrict__ deg,
        int* __restrict__ row_start, int* __restrict__ run,
        float* __restrict__ dinv, int N) {
    __shared__ int buf[1024];
    const int tid = threadIdx.x;
    const int P = (N + 1023) >> 10;
    int s = 0;
    for (int i = 0; i < P; ++i) {
        int idx = i * 1024 + tid;
        if (idx < N) s += cnt[idx];
    }
    buf[tid] = s;
    __syncthreads();
    for (int off = 1; off < 1024; off <<= 1) {   // inclusive Hillis-Steele
        int x = buf[tid];
        int a = (tid >= off) ? buf[tid - off] : 0;
        __syncthreads();
        buf[tid] = x + a;
        __syncthreads();
    }
    int r = buf[tid] - s;    // exclusive base for this thread's chunk
    for (int i = 0; i < P; ++i) {
        int idx = i * 1024 + tid;
        if (idx < N) {
            int c = cnt[idx];
            row_start[idx] = r;
            run[idx]       = r;
            dinv[idx]      = rsqrtf(deg[idx] + 1.0f);
            r += c;
        }
    }
}

// ---------------- X: direct scatter to final CSR position ------------------
__global__ __launch_bounds__(1024) void scatter_kernel(
        const int* __restrict__ src, const int* __restrict__ dst,
        const float* __restrict__ ew, int* __restrict__ run,
        int2* __restrict__ binned, int E) {
    int stride = gridDim.x * 1024;
    for (int e = blockIdx.x * 1024 + threadIdx.x; e < E; e += stride) {
        int d = dst[e];
        int pos = atomicAdd(&run[d], 1);
        binned[pos] = make_int2(src[e] << 7, __float_as_int(ew[e]));
    }
}

// --- GEMM: Y[r, stride 64](bf16) = dinv[r] * (X[N,K](fp32) @ W[K,M](fp32)) -
// All layers write bf16 rows of stride 64 elems (128B). M=40 leaves cols
// 40..63 stale (finite bf16 from layer-2 output) -- never read as output.
template <int K, int M>
__global__ __launch_bounds__(256) void gemm_kernel(const float* __restrict__ X,
        const float* __restrict__ W, const float* __restrict__ dinv,
        unsigned short* __restrict__ Y, int N) {
    constexpr int KP = K + 4;
    __shared__ float xs[64 * KP];
    __shared__ float ws[K * M];
    const int tid = threadIdx.x;
    const int row0 = blockIdx.x * 64;

    for (int i = tid * 4; i < K * M; i += 1024)
        *(float4*)&ws[i] = *(const float4*)&W[i];

    const int nrows = min(64, N - row0);
    for (int i = tid * 4; i < 64 * K; i += 1024) {
        int r = i / K, k = i % K;
        float4 v = f4zero();
        if (r < nrows) v = *(const float4*)&X[(size_t)(row0 + r) * K + k];
        *(float4*)&xs[r * KP + k] = v;
    }
    __syncthreads();

    const int ct = tid & 15, rt = tid >> 4;
    const int c = ct * 4;
    const bool cok = (c < M);
    float acc[4][4] = {};
    for (int k = 0; k < K; ++k) {
        float a0 = xs[(rt +  0) * KP + k];
        float a1 = xs[(rt + 16) * KP + k];
        float a2 = xs[(rt + 32) * KP + k];
        float a3 = xs[(rt + 48) * KP + k];
        float4 bv = cok ? *(const float4*)&ws[k * M + c] : f4zero();
        acc[0][0] += a0 * bv.x; acc[0][1] += a0 * bv.y; acc[0][2] += a0 * bv.z; acc[0][3] += a0 * bv.w;
        acc[1][0] += a1 * bv.x; acc[1][1] += a1 * bv.y; acc[1][2] += a1 * bv.z; acc[1][3] += a1 * bv.w;
        acc[2][0] += a2 * bv.x; acc[2][1] += a2 * bv.y; acc[2][2] += a2 * bv.z; acc[2][3] += a2 * bv.w;
        acc[3][0] += a3 * bv.x; acc[3][1] += a3 * bv.y; acc[3][2] += a3 * bv.z; acc[3][3] += a3 * bv.w;
    }
    if (cok) {
        #pragma unroll
        for (int i = 0; i < 4; ++i) {
            int r = row0 + rt + 16 * i;
            if (r < N) {
                float dd = dinv[r];
                ushort4 o;
                o.x = f2bf_rne(acc[i][0] * dd); o.y = f2bf_rne(acc[i][1] * dd);
                o.z = f2bf_rne(acc[i][2] * dd); o.w = f2bf_rne(acc[i][3] * dd);
                *(ushort4*)&Y[(size_t)r * 64 + c] = o;
            }
        }
    }
}

// ---------------- Aggregate (R15): bpermute edge distribution --------------
// xw: bf16 rows, stride 64 elems (128B), dinv-prescaled. One wave per node.
// 64-edge blocks vector-loaded int2 (double-buffered). Per 8-edge step:
// lane L serves edge t*8+(L>>3); {off,w} via 2 ds_bpermute; one
// global_load_dwordx4 covers 8 rows (8 lanes x 16B each); 8 unpack+fmac.
// out = dinv[d]*(sum_e ew*xw[s] + xw[d]) + b.
template <int FOUT, bool RELU>
__global__ __launch_bounds__(256) void agg_kernel(
        const unsigned short* __restrict__ xw,
        const int2* __restrict__ csr, const int* __restrict__ row_start,
        const int* __restrict__ row_cnt, const float* __restrict__ dinv,
        const float* __restrict__ bias, float* __restrict__ out, int N) {
    int wid = (int)((blockIdx.x * blockDim.x + threadIdx.x) >> 6);
    int lane = threadIdx.x & 63;
    if (wid >= N) return;

    const int2* row = csr + row_start[wid];
    const int   cnt = row_cnt[wid];
    const char* xwb = (const char*)xw;

    const int g = lane >> 3;                           // edge slot in step
    const unsigned li16 = (unsigned)(lane & 7) * 16u;  // byte chunk in row
    const int g4 = g << 2;                             // bpermute byte base

    float acc[8] = {0.f, 0.f, 0.f, 0.f, 0.f, 0.f, 0.f, 0.f};

    // prime block 0
    int2 edA = make_int2(0, 0);
    if (lane < cnt) edA = row[lane];                   // min(cnt,64) via lane<64

    for (int base = 0; base < cnt; base += 64) {
        const int m = min(cnt - base, 64);
        // prefetch next 64-edge block (overlaps with current processing)
        int2 edN = make_int2(0, 0);
        const int nb = base + 64;
        if (nb < cnt) {
            if (lane < cnt - nb) edN = row[nb + lane];
        }
        int bidx = g4;
        #pragma unroll 2
        for (int t = 0; t * 8 < m; ++t, bidx += 32) {
            unsigned off = (unsigned)__builtin_amdgcn_ds_bpermute(bidx, edA.x);
            unsigned wu  = (unsigned)__builtin_amdgcn_ds_bpermute(bidx, edA.y);
            const bool valid = (t * 8 + g) < m;
            off = valid ? off : 0u;
            float wf = valid ? __uint_as_float(wu) : 0.f;
            uint4 rv = *(const uint4*)(xwb + (size_t)(off + li16));
            acc[0] = fmaf(wf, bflo(rv.x), acc[0]);
            acc[1] = fmaf(wf, bfhi(rv.x), acc[1]);
            acc[2] = fmaf(wf, bflo(rv.y), acc[2]);
            acc[3] = fmaf(wf, bfhi(rv.y), acc[3]);
            acc[4] = fmaf(wf, bflo(rv.z), acc[4]);
            acc[5] = fmaf(wf, bfhi(rv.z), acc[5]);
            acc[6] = fmaf(wf, bflo(rv.w), acc[6]);
            acc[7] = fmaf(wf, bfhi(rv.w), acc[7]);
        }
        edA = edN;
    }

    // reduce across the 8 edge groups (lanes with same li)
    #pragma unroll
    for (int o = 8; o <= 32; o <<= 1) {
        #pragma unroll
        for (int t = 0; t < 8; ++t)
            acc[t] += __shfl_xor(acc[t], o);
    }

    if (lane < FOUT / 8) {   // g==0 lanes; features f0..f0+7
        const int f0 = lane * 8;
        uint4 sr = *(const uint4*)(xwb + ((unsigned)wid * 128u + li16));
        float dd = dinv[wid];
        float4 bv0 = *(const float4*)&bias[f0];
        float4 bv1 = *(const float4*)&bias[f0 + 4];
        float r0 = dd * (acc[0] + bflo(sr.x)) + bv0.x;
        float r1 = dd * (acc[1] + bfhi(sr.x)) + bv0.y;
        float r2 = dd * (acc[2] + bflo(sr.y)) + bv0.z;
        float r3 = dd * (acc[3] + bfhi(sr.y)) + bv0.w;
        float r4 = dd * (acc[4] + bflo(sr.z)) + bv1.x;
        float r5 = dd * (acc[5] + bfhi(sr.z)) + bv1.y;
        float r6 = dd * (acc[6] + bflo(sr.w)) + bv1.z;
        float r7 = dd * (acc[7] + bfhi(sr.w)) + bv1.w;
        if (RELU) {
            r0 = fmaxf(r0, 0.f); r1 = fmaxf(r1, 0.f); r2 = fmaxf(r2, 0.f); r3 = fmaxf(r3, 0.f);
            r4 = fmaxf(r4, 0.f); r5 = fmaxf(r5, 0.f); r6 = fmaxf(r6, 0.f); r7 = fmaxf(r7, 0.f);
        }
        *(float4*)&out[(size_t)wid * FOUT + f0]     = make_float4(r0, r1, r2, r3);
        *(float4*)&out[(size_t)wid * FOUT + f0 + 4] = make_float4(r4, r5, r6, r7);
    }
}

static inline size_t ws_align(size_t x) { return (x + 255) & ~(size_t)255; }

extern "C" void kernel_launch(void* const* d_in, const int* in_sizes, int n_in,
                              void* d_out, int out_size, void* d_ws, size_t ws_size,
                              hipStream_t stream) {
    const float* x  = (const float*)d_in[0];
    const int*   ei = (const int*)d_in[1];
    const float* ew = (const float*)d_in[2];
    const float* W1 = (const float*)d_in[3];
    const float* b1 = (const float*)d_in[4];
    const float* W2 = (const float*)d_in[5];
    const float* b2 = (const float*)d_in[6];
    const float* W3 = (const float*)d_in[7];
    const float* b3 = (const float*)d_in[8];
    float* out = (float*)d_out;

    const int N = in_sizes[0] / 128;   // 50000
    const int E = in_sizes[1] / 2;     // 1600000
    const int* src = ei;
    const int* dst = ei + E;

    char* p = (char*)d_ws;
    size_t off = 0;
    auto alloc = [&](size_t bytes) -> char* {
        char* q = p + off;
        off = ws_align(off + bytes);
        return q;
    };
    int*   row_start = (int*)  alloc((size_t)N * 4);
    int*   row_cnt   = (int*)  alloc((size_t)N * 4);   // = cnt histogram
    int*   run       = (int*)  alloc((size_t)N * 4);   // scatter cursors
    float* deg       = (float*)alloc((size_t)N * 4);
    float* dinv      = (float*)alloc((size_t)N * 4);
    unsigned short* xwbuf = (unsigned short*)alloc((size_t)N * 64 * 2);  // bf16, stride 64
    float* hbuf      = (float*)alloc((size_t)N * 64 * 4);                // fp32 h
    int2*  binned    = (int2*) alloc((size_t)E * 8);

    const int zb = (N + 1023) / 1024;       // 49
    const int eb = 512;                     // grid-stride blocks for E loops
    const int gb = (N + 63) / 64;           // 782 GEMM tiles
    const int ab = (N + 3) / 4;             // one wave per node

    zero_kernel<<<zb, 1024, 0, stream>>>(row_cnt, deg, N);
    count_kernel<<<eb, 1024, 0, stream>>>(dst, ew, row_cnt, deg, E);
    scan_kernel<<<1, 1024, 0, stream>>>(row_cnt, deg, row_start, run, dinv, N);
    scatter_kernel<<<eb, 1024, 0, stream>>>(src, dst, ew, run, binned, E);

    gemm_kernel<128, 64><<<gb, 256, 0, stream>>>(x, W1, dinv, xwbuf, N);
    agg_kernel<64, true ><<<ab, 256, 0, stream>>>(xwbuf, binned, row_start, row_cnt, dinv, b1, hbuf, N);
    gemm_kernel<64, 64><<<gb, 256, 0, stream>>>(hbuf, W2, dinv, xwbuf, N);
    agg_kernel<64, true ><<<ab, 256, 0, stream>>>(xwbuf, binned, row_start, row_cnt, dinv, b2, hbuf, N);
    gemm_kernel<64, 40><<<gb, 256, 0, stream>>>(hbuf, W3, dinv, xwbuf, N);
    agg_kernel<40, false><<<ab, 256, 0, stream>>>(xwbuf, binned, row_start, row_cnt, dinv, b3, out, N);
}

// Round 7
// 325.806 us; speedup vs baseline: 1.6374x; 1.6374x over previous
//
#include <hip/hip_runtime.h>

// GCN 3-layer: out = GCNconv3(relu(GCNconv2(relu(GCNconv1(x)))))
//
// R17 = R15 (267us-class) with xw split into two L2-resident 3.2MB planes
// and agg run as two half-feature passes, 16 edges per VMEM gather.
// R16 lesson: cross-XCD global atomics write through the fabric (99.6MB
// writes for 400KB of counters, 149us) -- deterministic LDS binning only.
// Agg model: 7.3 cyc/line ~= MSHR(32)/blended-latency(~295cyc; 6.4MB table
// spans L2+LLC). This round tests the latency term with instruction count
// held constant (R11's null was instruction-bound, so residency was masked):
//   - plane0 = feats [0,32), plane1 = feats [32,64), rows 64B (layer3
//     plane1: feats [32,40), rows 16B)
//   - per pass: 4 lanes per row -> 1 global_load_dwordx4 = 16 edges
//     (layer3 plane1: 1 lane/row -> 64 edges/instr)
//   - {off,w} to lanes via 2 ds_bpermute per step; edge blocks int2-loaded,
//     double-buffered (R15)
//   - total lines/edge still 2; VMEM instrs/layer still E/8
//
//   A1. bin_count: per-tile 256-bin LDS histogram -> cnt[bin][tile]
//   A2. bin_scan: block per bin scans tile counts -> exclusive base + total
//   A3. bin_scatter: LDS sort per 4096-edge tile, flush to precomputed base
//   B.  bin_group: per-bin counting sort -> CSR {src*64, ew} + deg/dinv
//   C.  per layer: fp32 GEMM -> bf16 planes, dinv-prescaled
//   D.  agg passes: out[:,COFF..] = dinv[d]*(sum_e ew*P[s] + P[d]) + b

#define TILE 4096
#define BCAP_MAX 9216   // per-bin capacity; bin load ~Binom mean 8163 sd 90

static __device__ __forceinline__ float4 f4zero() { return make_float4(0.f, 0.f, 0.f, 0.f); }

static __device__ __forceinline__ unsigned short f2bf_rne(float x) {
    unsigned u = __float_as_uint(x);
    u += 0x7FFFu + ((u >> 16) & 1u);     // round-to-nearest-even
    return (unsigned short)(u >> 16);
}
static __device__ __forceinline__ float bflo(unsigned u) { return __uint_as_float(u << 16); }
static __device__ __forceinline__ float bfhi(unsigned u) { return __uint_as_float(u & 0xffff0000u); }

// ---------------- A1: per-tile bin histogram -> cnt[bin][tile] -------------
__global__ __launch_bounds__(1024) void bin_count_kernel(
        const int* __restrict__ dst, int* __restrict__ cnt, int E, int ntiles) {
    __shared__ int h[256];
    const int tid = threadIdx.x;
    const int t = blockIdx.x;
    if (tid < 256) h[tid] = 0;
    __syncthreads();
    const int e0 = t * TILE;
    #pragma unroll
    for (int j = 0; j < 4; ++j) {
        int e = e0 + j * 1024 + tid;
        if (e < E) atomicAdd(&h[dst[e] >> 8], 1);
    }
    __syncthreads();
    if (tid < 256) cnt[tid * ntiles + t] = h[tid];
}

// ---------------- A2: per-bin exclusive scan over tiles --------------------
__global__ __launch_bounds__(512) void bin_scan_kernel(
        int* __restrict__ cnt, int* __restrict__ bintotal, int ntiles) {
    __shared__ int buf[512];
    const int b = blockIdx.x;
    const int tid = threadIdx.x;
    int v = (tid < ntiles) ? cnt[b * ntiles + tid] : 0;
    buf[tid] = v;
    __syncthreads();
    for (int off = 1; off < 512; off <<= 1) {   // inclusive Hillis-Steele
        int x = buf[tid];
        int a = (tid >= off) ? buf[tid - off] : 0;
        __syncthreads();
        buf[tid] = x + a;
        __syncthreads();
    }
    if (tid < ntiles) cnt[b * ntiles + tid] = buf[tid] - v;   // exclusive base
    if (tid == 0) bintotal[b] = buf[511];
}

// ---------------- A3: tile-level LDS binning, deterministic flush ----------
__global__ __launch_bounds__(1024) void bin_scatter_kernel(
        const int* __restrict__ src, const int* __restrict__ dst,
        const float* __restrict__ ew, const int* __restrict__ cntbase,
        int2* __restrict__ binned, int E, int bcap, int ntiles) {
    __shared__ int cnt[256];
    __shared__ int scan[256];
    __shared__ int gbase[256];
    __shared__ int2 sorted[TILE];
    __shared__ unsigned char binof[TILE];
    const int tid = threadIdx.x;
    const int t = blockIdx.x;
    const int e0 = t * TILE;

    if (tid < 256) cnt[tid] = 0;
    __syncthreads();

    int mypk[4]; float myew[4]; int mybin[4]; int myrank[4]; bool myok[4];
    #pragma unroll
    for (int j = 0; j < 4; ++j) {
        int e = e0 + j * 1024 + tid;
        myok[j] = (e < E);
        if (myok[j]) {
            int d = dst[e];
            int s = src[e];
            myew[j]   = ew[e];
            mybin[j]  = d >> 8;
            mypk[j]   = (s << 8) | (d & 255);     // src:24b | dst_local:8b
            myrank[j] = atomicAdd(&cnt[mybin[j]], 1);
        }
    }
    __syncthreads();
    if (tid < 256) scan[tid] = cnt[tid];
    __syncthreads();
    for (int off = 1; off < 256; off <<= 1) {     // inclusive Hillis-Steele
        int v = 0;
        if (tid < 256) { v = scan[tid]; if (tid >= off) v += scan[tid - off]; }
        __syncthreads();
        if (tid < 256) scan[tid] = v;
        __syncthreads();
    }
    if (tid < 256) gbase[tid] = cntbase[tid * ntiles + t];   // no atomics
    __syncthreads();
    #pragma unroll
    for (int j = 0; j < 4; ++j) {
        if (myok[j]) {
            int b = mybin[j];
            int slot = (scan[b] - cnt[b]) + myrank[j];   // excl prefix + rank
            sorted[slot] = make_int2(mypk[j], __float_as_int(myew[j]));
            binof[slot]  = (unsigned char)b;
        }
    }
    __syncthreads();
    const int total = scan[255];
    for (int i = tid; i < total; i += 1024) {
        int b = binof[i];
        int pos = gbase[b] + (i - (scan[b] - cnt[b]));
        if (pos < bcap)   // statistically unreachable; prevents OOB
            binned[(size_t)b * bcap + pos] = sorted[i];
    }
}

// ---------------- B: per-bin counting sort -> CSR (+ deg/dinv) -------------
// Final CSR payload: {src*64 (plane0 row byte offset), ew}
__global__ __launch_bounds__(1024) void bin_group_kernel(
        int2* __restrict__ binned, const int* __restrict__ bintotal,
        int* __restrict__ row_start, int* __restrict__ row_cnt,
        float* __restrict__ dinv, int N, int bcap) {
    __shared__ int   cntl[256];
    __shared__ float degl[256];
    __shared__ int   scan[256];
    __shared__ int   run[256];
    __shared__ int2  sorted[BCAP_MAX];
    const int b = blockIdx.x;
    const int tid = threadIdx.x;
    int n = bintotal[b];
    if (n > bcap) n = bcap;
    if (tid < 256) { cntl[tid] = 0; degl[tid] = 0.f; }
    __syncthreads();

    int2* seg = binned + (size_t)b * bcap;
    for (int i = tid; i < n; i += 1024) {
        int2 v = seg[i];
        int dl = v.x & 255;
        atomicAdd(&cntl[dl], 1);
        atomicAdd(&degl[dl], __int_as_float(v.y));
    }
    __syncthreads();
    if (tid < 256) scan[tid] = cntl[tid];
    __syncthreads();
    for (int off = 1; off < 256; off <<= 1) {
        int v = 0;
        if (tid < 256) { v = scan[tid]; if (tid >= off) v += scan[tid - off]; }
        __syncthreads();
        if (tid < 256) scan[tid] = v;
        __syncthreads();
    }
    if (tid < 256) {
        int ex = scan[tid] - cntl[tid];
        int d = (b << 8) + tid;
        if (d < N) {
            row_start[d] = b * bcap + ex;
            row_cnt[d]   = cntl[tid];
            dinv[d]      = rsqrtf(degl[tid] + 1.0f);
        }
        run[tid] = ex;
    }
    __syncthreads();
    for (int i = tid; i < n; i += 1024) {
        int2 v = seg[i];
        int dl = v.x & 255;
        int r = atomicAdd(&run[dl], 1);
        sorted[r] = make_int2((v.x >> 8) << 6, v.y);   // {src*64, ew}
    }
    __syncthreads();
    for (int i = tid; i < n; i += 1024)          // in-place: reads done above
        seg[i] = sorted[i];
}

// --- GEMM: planes(bf16) = dinv[r] * (X[N,K](fp32) @ W[K,M](fp32)) ----------
// plane0: feats [0,32) rows 64B at Y[0]; plane1: feats [32,M) at Y[N*32],
// rows 64B (M=64) or 16B (M=40).
template <int K, int M>
__global__ __launch_bounds__(256) void gemm_kernel(const float* __restrict__ X,
        const float* __restrict__ W, const float* __restrict__ dinv,
        unsigned short* __restrict__ Y, int N) {
    constexpr int KP = K + 4;
    constexpr int P1S = (M == 40) ? 8 : 32;    // plane1 row stride (elems)
    __shared__ float xs[64 * KP];
    __shared__ float ws[K * M];
    const int tid = threadIdx.x;
    const int row0 = blockIdx.x * 64;

    for (int i = tid * 4; i < K * M; i += 1024)
        *(float4*)&ws[i] = *(const float4*)&W[i];

    const int nrows = min(64, N - row0);
    for (int i = tid * 4; i < 64 * K; i += 1024) {
        int r = i / K, k = i % K;
        float4 v = f4zero();
        if (r < nrows) v = *(const float4*)&X[(size_t)(row0 + r) * K + k];
        *(float4*)&xs[r * KP + k] = v;
    }
    __syncthreads();

    const int ct = tid & 15, rt = tid >> 4;
    const int c = ct * 4;
    const bool cok = (c < M);
    float acc[4][4] = {};
    for (int k = 0; k < K; ++k) {
        float a0 = xs[(rt +  0) * KP + k];
        float a1 = xs[(rt + 16) * KP + k];
        float a2 = xs[(rt + 32) * KP + k];
        float a3 = xs[(rt + 48) * KP + k];
        float4 bv = cok ? *(const float4*)&ws[k * M + c] : f4zero();
        acc[0][0] += a0 * bv.x; acc[0][1] += a0 * bv.y; acc[0][2] += a0 * bv.z; acc[0][3] += a0 * bv.w;
        acc[1][0] += a1 * bv.x; acc[1][1] += a1 * bv.y; acc[1][2] += a1 * bv.z; acc[1][3] += a1 * bv.w;
        acc[2][0] += a2 * bv.x; acc[2][1] += a2 * bv.y; acc[2][2] += a2 * bv.z; acc[2][3] += a2 * bv.w;
        acc[3][0] += a3 * bv.x; acc[3][1] += a3 * bv.y; acc[3][2] += a3 * bv.z; acc[3][3] += a3 * bv.w;
    }
    if (cok) {
        #pragma unroll
        for (int i = 0; i < 4; ++i) {
            int r = row0 + rt + 16 * i;
            if (r < N) {
                float dd = dinv[r];
                ushort4 o;
                o.x = f2bf_rne(acc[i][0] * dd); o.y = f2bf_rne(acc[i][1] * dd);
                o.z = f2bf_rne(acc[i][2] * dd); o.w = f2bf_rne(acc[i][3] * dd);
                unsigned short* dp;
                if (c < 32) dp = &Y[(size_t)r * 32 + c];
                else        dp = &Y[(size_t)N * 32 + (size_t)r * P1S + (c - 32)];
                *(ushort4*)dp = o;
            }
        }
    }
}

// ---------------- Aggregate pass (R17): L2-resident plane gather -----------
// plane: bf16 rows of FH feats (FH*2 bytes), dinv-prescaled.
// FH=32: 4 lanes/row, 16 edges per dwordx4; FH=8: 1 lane/row, 64 edges.
// CSR offsets are src*64 (plane0 bytes); FH=8 rows use off>>2 (src*16).
// out[:,COFF..COFF+FH) = dinv[d]*(sum_e ew*plane[s] + plane[d]) + b[COFF..).
template <int FH, int FTOT, int COFF, bool RELU>
__global__ __launch_bounds__(256) void agg_pass_kernel(
        const unsigned short* __restrict__ plane,
        const int2* __restrict__ csr, const int* __restrict__ row_start,
        const int* __restrict__ row_cnt, const float* __restrict__ dinv,
        const float* __restrict__ bias, float* __restrict__ out, int N) {
    constexpr int LPR = FH / 8;        // lanes per row: 4 or 1
    constexpr int EPS = 64 / LPR;      // edges per step: 16 or 64
    constexpr int SH  = (FH == 32) ? 0 : 2;   // src*64 -> row byte offset
    int wid = (int)((blockIdx.x * blockDim.x + threadIdx.x) >> 6);
    int lane = threadIdx.x & 63;
    if (wid >= N) return;

    const int2* row = csr + row_start[wid];
    const int   cnt = row_cnt[wid];
    const char* xwb = (const char*)plane;

    const int g = lane / LPR;                            // edge slot in step
    const unsigned li16 = (unsigned)(lane % LPR) * 16u;  // byte chunk in row

    float acc[8] = {0.f, 0.f, 0.f, 0.f, 0.f, 0.f, 0.f, 0.f};

    // prime block 0
    int2 edA = make_int2(0, 0);
    if (lane < cnt) edA = row[lane];

    for (int base = 0; base < cnt; base += 64) {
        const int m = min(cnt - base, 64);
        // prefetch next 64-edge block
        int2 edN = make_int2(0, 0);
        const int nb = base + 64;
        if (nb < cnt) {
            if (lane < cnt - nb) edN = row[nb + lane];
        }
        #pragma unroll
        for (int t = 0; t < 64 / EPS; ++t) {
            if (t * EPS >= m) break;
            unsigned off, wu;
            if (EPS == 64) {             // lane == edge slot: direct
                off = (unsigned)edA.x;
                wu  = (unsigned)edA.y;
            } else {
                int bidx = (t * EPS + g) << 2;
                off = (unsigned)__builtin_amdgcn_ds_bpermute(bidx, edA.x);
                wu  = (unsigned)__builtin_amdgcn_ds_bpermute(bidx, edA.y);
            }
            const bool valid = (t * EPS + g) < m;
            off = valid ? off : 0u;
            float wf = valid ? __uint_as_float(wu) : 0.f;
            uint4 rv = *(const uint4*)(xwb + (size_t)((off >> SH) + li16));
            acc[0] = fmaf(wf, bflo(rv.x), acc[0]);
            acc[1] = fmaf(wf, bfhi(rv.x), acc[1]);
            acc[2] = fmaf(wf, bflo(rv.y), acc[2]);
            acc[3] = fmaf(wf, bfhi(rv.y), acc[3]);
            acc[4] = fmaf(wf, bflo(rv.z), acc[4]);
            acc[5] = fmaf(wf, bfhi(rv.z), acc[5]);
            acc[6] = fmaf(wf, bflo(rv.w), acc[6]);
            acc[7] = fmaf(wf, bfhi(rv.w), acc[7]);
        }
        edA = edN;
    }

    // reduce across edge groups (lanes sharing the same li)
    #pragma unroll
    for (int o = LPR; o <= 32; o <<= 1) {
        #pragma unroll
        for (int t = 0; t < 8; ++t)
            acc[t] += __shfl_xor(acc[t], o);
    }

    if (lane < LPR) {   // writers: features COFF+lane*8 .. +8
        const int f0 = lane * 8;
        uint4 sr = *(const uint4*)(xwb + (size_t)wid * (FH * 2) + (unsigned)lane * 16u);
        float dd = dinv[wid];
        float4 bv0 = *(const float4*)&bias[COFF + f0];
        float4 bv1 = *(const float4*)&bias[COFF + f0 + 4];
        float r0 = dd * (acc[0] + bflo(sr.x)) + bv0.x;
        float r1 = dd * (acc[1] + bfhi(sr.x)) + bv0.y;
        float r2 = dd * (acc[2] + bflo(sr.y)) + bv0.z;
        float r3 = dd * (acc[3] + bfhi(sr.y)) + bv0.w;
        float r4 = dd * (acc[4] + bflo(sr.z)) + bv1.x;
        float r5 = dd * (acc[5] + bfhi(sr.z)) + bv1.y;
        float r6 = dd * (acc[6] + bflo(sr.w)) + bv1.z;
        float r7 = dd * (acc[7] + bfhi(sr.w)) + bv1.w;
        if (RELU) {
            r0 = fmaxf(r0, 0.f); r1 = fmaxf(r1, 0.f); r2 = fmaxf(r2, 0.f); r3 = fmaxf(r3, 0.f);
            r4 = fmaxf(r4, 0.f); r5 = fmaxf(r5, 0.f); r6 = fmaxf(r6, 0.f); r7 = fmaxf(r7, 0.f);
        }
        *(float4*)&out[(size_t)wid * FTOT + COFF + f0]     = make_float4(r0, r1, r2, r3);
        *(float4*)&out[(size_t)wid * FTOT + COFF + f0 + 4] = make_float4(r4, r5, r6, r7);
    }
}

static inline size_t ws_align(size_t x) { return (x + 255) & ~(size_t)255; }

extern "C" void kernel_launch(void* const* d_in, const int* in_sizes, int n_in,
                              void* d_out, int out_size, void* d_ws, size_t ws_size,
                              hipStream_t stream) {
    const float* x  = (const float*)d_in[0];
    const int*   ei = (const int*)d_in[1];
    const float* ew = (const float*)d_in[2];
    const float* W1 = (const float*)d_in[3];
    const float* b1 = (const float*)d_in[4];
    const float* W2 = (const float*)d_in[5];
    const float* b2 = (const float*)d_in[6];
    const float* W3 = (const float*)d_in[7];
    const float* b3 = (const float*)d_in[8];
    float* out = (float*)d_out;

    const int N = in_sizes[0] / 128;   // 50000
    const int E = in_sizes[1] / 2;     // 1600000
    const int* src = ei;
    const int* dst = ei + E;
    const int nbins = (N + 255) >> 8;         // 196
    const int ntiles = (E + TILE - 1) / TILE; // 391 (must be <= 512 for scan)

    char* p = (char*)d_ws;
    size_t off = 0;
    auto alloc = [&](size_t bytes) -> char* {
        char* q = p + off;
        off = ws_align(off + bytes);
        return q;
    };
    int*   row_start = (int*)  alloc((size_t)N * 4);
    int*   row_cnt   = (int*)  alloc((size_t)N * 4);
    float* dinv      = (float*)alloc((size_t)N * 4);
    int*   cntbase   = (int*)  alloc((size_t)256 * ntiles * 4);  // [bin][tile]
    int*   bintotal  = (int*)  alloc((size_t)256 * 4);
    unsigned short* xwbuf = (unsigned short*)alloc((size_t)N * 64 * 2);  // bf16 planes
    float* hbuf      = (float*)alloc((size_t)N * 64 * 4);                // fp32 h
    size_t remain = (ws_size > off) ? (ws_size - off) : 0;
    int bcap = (int)(remain / ((size_t)nbins * 8));
    if (bcap > BCAP_MAX) bcap = BCAP_MAX;
    int2* binned = (int2*)alloc((size_t)nbins * (size_t)bcap * 8);

    const unsigned short* plane1 = xwbuf + (size_t)N * 32;

    const int gb = (N + 63) / 64;           // 782 GEMM tiles
    const int ab = (N + 3) / 4;             // one wave per node

    bin_count_kernel<<<ntiles, 1024, 0, stream>>>(dst, cntbase, E, ntiles);
    bin_scan_kernel<<<256, 512, 0, stream>>>(cntbase, bintotal, ntiles);
    bin_scatter_kernel<<<ntiles, 1024, 0, stream>>>(src, dst, ew, cntbase, binned, E, bcap, ntiles);
    bin_group_kernel<<<nbins, 1024, 0, stream>>>(binned, bintotal, row_start, row_cnt, dinv, N, bcap);

    gemm_kernel<128, 64><<<gb, 256, 0, stream>>>(x, W1, dinv, xwbuf, N);
    agg_pass_kernel<32, 64,  0, true ><<<ab, 256, 0, stream>>>(xwbuf,  binned, row_start, row_cnt, dinv, b1, hbuf, N);
    agg_pass_kernel<32, 64, 32, true ><<<ab, 256, 0, stream>>>(plane1, binned, row_start, row_cnt, dinv, b1, hbuf, N);
    gemm_kernel<64, 64><<<gb, 256, 0, stream>>>(hbuf, W2, dinv, xwbuf, N);
    agg_pass_kernel<32, 64,  0, true ><<<ab, 256, 0, stream>>>(xwbuf,  binned, row_start, row_cnt, dinv, b2, hbuf, N);
    agg_pass_kernel<32, 64, 32, true ><<<ab, 256, 0, stream>>>(plane1, binned, row_start, row_cnt, dinv, b2, hbuf, N);
    gemm_kernel<64, 40><<<gb, 256, 0, stream>>>(hbuf, W3, dinv, xwbuf, N);
    agg_pass_kernel<32, 40,  0, false><<<ab, 256, 0, stream>>>(xwbuf,  binned, row_start, row_cnt, dinv, b3, out, N);
    agg_pass_kernel< 8, 40, 32, false><<<ab, 256, 0, stream>>>(plane1, binned, row_start, row_cnt, dinv, b3, out, N);
}

// Round 8
// 270.368 us; speedup vs baseline: 1.9731x; 1.2050x over previous
//
#include <hip/hip_runtime.h>

// GCN 3-layer: out = GCNconv3(relu(GCNconv2(relu(GCNconv1(x)))))
//
// R18 = R15 single-pass structure + 2-nodes-per-wave ILP in agg.
// Evidence: R15 vs R17 solves to ~19us FIXED cost per edge-list pass
// (independent of gather instr count) + ~19us instr work at E/8 gathers.
// Fixed part = per-wave serial chain (descriptor load -> edge block load
// -> bpermute -> gather -> reduce -> store) with only 50K waves (~5-8
// resident/SIMD) to hide it. R18 halves wave count: wave w owns nodes
// {2w, 2w+1} with fully independent register chains interleaved in the
// inner loop (ILP-2), epilogue stores A from lanes 0-7, B from lanes 8-15.
// Gather structure unchanged (8 edges per global_load_dwordx4, bpermute
// distribution, double-buffered edge blocks). R16 lesson: no global atomics.
//
//   A1. bin_count: per-tile 256-bin LDS histogram -> cnt[bin][tile]
//   A2. bin_scan: block per bin scans tile counts -> exclusive base + total
//   A3. bin_scatter: LDS sort per 4096-edge tile, flush to precomputed base
//   B.  bin_group: per-bin counting sort -> CSR {src*128, ew} + deg/dinv
//   C.  per layer: fp32 GEMM -> bf16 Y[r, stride 64] = dinv[r]*(X@W)[r]
//   D.  agg: out = dinv[d]*(sum_e ew*Y[s] + Y[d]) + b, one wave per 2 nodes

#define TILE 4096
#define BCAP_MAX 9216   // per-bin capacity; bin load ~Binom mean 8163 sd 90

static __device__ __forceinline__ float4 f4zero() { return make_float4(0.f, 0.f, 0.f, 0.f); }

static __device__ __forceinline__ unsigned short f2bf_rne(float x) {
    unsigned u = __float_as_uint(x);
    u += 0x7FFFu + ((u >> 16) & 1u);     // round-to-nearest-even
    return (unsigned short)(u >> 16);
}
static __device__ __forceinline__ float bflo(unsigned u) { return __uint_as_float(u << 16); }
static __device__ __forceinline__ float bfhi(unsigned u) { return __uint_as_float(u & 0xffff0000u); }

// ---------------- A1: per-tile bin histogram -> cnt[bin][tile] -------------
__global__ __launch_bounds__(1024) void bin_count_kernel(
        const int* __restrict__ dst, int* __restrict__ cnt, int E, int ntiles) {
    __shared__ int h[256];
    const int tid = threadIdx.x;
    const int t = blockIdx.x;
    if (tid < 256) h[tid] = 0;
    __syncthreads();
    const int e0 = t * TILE;
    #pragma unroll
    for (int j = 0; j < 4; ++j) {
        int e = e0 + j * 1024 + tid;
        if (e < E) atomicAdd(&h[dst[e] >> 8], 1);
    }
    __syncthreads();
    if (tid < 256) cnt[tid * ntiles + t] = h[tid];
}

// ---------------- A2: per-bin exclusive scan over tiles --------------------
__global__ __launch_bounds__(512) void bin_scan_kernel(
        int* __restrict__ cnt, int* __restrict__ bintotal, int ntiles) {
    __shared__ int buf[512];
    const int b = blockIdx.x;
    const int tid = threadIdx.x;
    int v = (tid < ntiles) ? cnt[b * ntiles + tid] : 0;
    buf[tid] = v;
    __syncthreads();
    for (int off = 1; off < 512; off <<= 1) {   // inclusive Hillis-Steele
        int x = buf[tid];
        int a = (tid >= off) ? buf[tid - off] : 0;
        __syncthreads();
        buf[tid] = x + a;
        __syncthreads();
    }
    if (tid < ntiles) cnt[b * ntiles + tid] = buf[tid] - v;   // exclusive base
    if (tid == 0) bintotal[b] = buf[511];
}

// ---------------- A3: tile-level LDS binning, deterministic flush ----------
__global__ __launch_bounds__(1024) void bin_scatter_kernel(
        const int* __restrict__ src, const int* __restrict__ dst,
        const float* __restrict__ ew, const int* __restrict__ cntbase,
        int2* __restrict__ binned, int E, int bcap, int ntiles) {
    __shared__ int cnt[256];
    __shared__ int scan[256];
    __shared__ int gbase[256];
    __shared__ int2 sorted[TILE];
    __shared__ unsigned char binof[TILE];
    const int tid = threadIdx.x;
    const int t = blockIdx.x;
    const int e0 = t * TILE;

    if (tid < 256) cnt[tid] = 0;
    __syncthreads();

    int mypk[4]; float myew[4]; int mybin[4]; int myrank[4]; bool myok[4];
    #pragma unroll
    for (int j = 0; j < 4; ++j) {
        int e = e0 + j * 1024 + tid;
        myok[j] = (e < E);
        if (myok[j]) {
            int d = dst[e];
            int s = src[e];
            myew[j]   = ew[e];
            mybin[j]  = d >> 8;
            mypk[j]   = (s << 8) | (d & 255);     // src:24b | dst_local:8b
            myrank[j] = atomicAdd(&cnt[mybin[j]], 1);
        }
    }
    __syncthreads();
    if (tid < 256) scan[tid] = cnt[tid];
    __syncthreads();
    for (int off = 1; off < 256; off <<= 1) {     // inclusive Hillis-Steele
        int v = 0;
        if (tid < 256) { v = scan[tid]; if (tid >= off) v += scan[tid - off]; }
        __syncthreads();
        if (tid < 256) scan[tid] = v;
        __syncthreads();
    }
    if (tid < 256) gbase[tid] = cntbase[tid * ntiles + t];   // no atomics
    __syncthreads();
    #pragma unroll
    for (int j = 0; j < 4; ++j) {
        if (myok[j]) {
            int b = mybin[j];
            int slot = (scan[b] - cnt[b]) + myrank[j];   // excl prefix + rank
            sorted[slot] = make_int2(mypk[j], __float_as_int(myew[j]));
            binof[slot]  = (unsigned char)b;
        }
    }
    __syncthreads();
    const int total = scan[255];
    for (int i = tid; i < total; i += 1024) {
        int b = binof[i];
        int pos = gbase[b] + (i - (scan[b] - cnt[b]));
        if (pos < bcap)   // statistically unreachable; prevents OOB
            binned[(size_t)b * bcap + pos] = sorted[i];
    }
}

// ---------------- B: per-bin counting sort -> CSR (+ deg/dinv) -------------
// Final CSR payload: {src*128 (row byte offset, stride-64 bf16 rows), ew}
__global__ __launch_bounds__(1024) void bin_group_kernel(
        int2* __restrict__ binned, const int* __restrict__ bintotal,
        int* __restrict__ row_start, int* __restrict__ row_cnt,
        float* __restrict__ dinv, int N, int bcap) {
    __shared__ int   cntl[256];
    __shared__ float degl[256];
    __shared__ int   scan[256];
    __shared__ int   run[256];
    __shared__ int2  sorted[BCAP_MAX];
    const int b = blockIdx.x;
    const int tid = threadIdx.x;
    int n = bintotal[b];
    if (n > bcap) n = bcap;
    if (tid < 256) { cntl[tid] = 0; degl[tid] = 0.f; }
    __syncthreads();

    int2* seg = binned + (size_t)b * bcap;
    for (int i = tid; i < n; i += 1024) {
        int2 v = seg[i];
        int dl = v.x & 255;
        atomicAdd(&cntl[dl], 1);
        atomicAdd(&degl[dl], __int_as_float(v.y));
    }
    __syncthreads();
    if (tid < 256) scan[tid] = cntl[tid];
    __syncthreads();
    for (int off = 1; off < 256; off <<= 1) {
        int v = 0;
        if (tid < 256) { v = scan[tid]; if (tid >= off) v += scan[tid - off]; }
        __syncthreads();
        if (tid < 256) scan[tid] = v;
        __syncthreads();
    }
    if (tid < 256) {
        int ex = scan[tid] - cntl[tid];
        int d = (b << 8) + tid;
        if (d < N) {
            row_start[d] = b * bcap + ex;
            row_cnt[d]   = cntl[tid];
            dinv[d]      = rsqrtf(degl[tid] + 1.0f);
        }
        run[tid] = ex;
    }
    __syncthreads();
    for (int i = tid; i < n; i += 1024) {
        int2 v = seg[i];
        int dl = v.x & 255;
        int r = atomicAdd(&run[dl], 1);
        sorted[r] = make_int2((v.x >> 8) << 7, v.y);   // {src*128, ew}
    }
    __syncthreads();
    for (int i = tid; i < n; i += 1024)          // in-place: reads done above
        seg[i] = sorted[i];
}

// --- GEMM: Y[r, stride 64](bf16) = dinv[r] * (X[N,K](fp32) @ W[K,M](fp32)) -
template <int K, int M>
__global__ __launch_bounds__(256) void gemm_kernel(const float* __restrict__ X,
        const float* __restrict__ W, const float* __restrict__ dinv,
        unsigned short* __restrict__ Y, int N) {
    constexpr int KP = K + 4;
    __shared__ float xs[64 * KP];
    __shared__ float ws[K * M];
    const int tid = threadIdx.x;
    const int row0 = blockIdx.x * 64;

    for (int i = tid * 4; i < K * M; i += 1024)
        *(float4*)&ws[i] = *(const float4*)&W[i];

    const int nrows = min(64, N - row0);
    for (int i = tid * 4; i < 64 * K; i += 1024) {
        int r = i / K, k = i % K;
        float4 v = f4zero();
        if (r < nrows) v = *(const float4*)&X[(size_t)(row0 + r) * K + k];
        *(float4*)&xs[r * KP + k] = v;
    }
    __syncthreads();

    const int ct = tid & 15, rt = tid >> 4;
    const int c = ct * 4;
    const bool cok = (c < M);
    float acc[4][4] = {};
    for (int k = 0; k < K; ++k) {
        float a0 = xs[(rt +  0) * KP + k];
        float a1 = xs[(rt + 16) * KP + k];
        float a2 = xs[(rt + 32) * KP + k];
        float a3 = xs[(rt + 48) * KP + k];
        float4 bv = cok ? *(const float4*)&ws[k * M + c] : f4zero();
        acc[0][0] += a0 * bv.x; acc[0][1] += a0 * bv.y; acc[0][2] += a0 * bv.z; acc[0][3] += a0 * bv.w;
        acc[1][0] += a1 * bv.x; acc[1][1] += a1 * bv.y; acc[1][2] += a1 * bv.z; acc[1][3] += a1 * bv.w;
        acc[2][0] += a2 * bv.x; acc[2][1] += a2 * bv.y; acc[2][2] += a2 * bv.z; acc[2][3] += a2 * bv.w;
        acc[3][0] += a3 * bv.x; acc[3][1] += a3 * bv.y; acc[3][2] += a3 * bv.z; acc[3][3] += a3 * bv.w;
    }
    if (cok) {
        #pragma unroll
        for (int i = 0; i < 4; ++i) {
            int r = row0 + rt + 16 * i;
            if (r < N) {
                float dd = dinv[r];
                ushort4 o;
                o.x = f2bf_rne(acc[i][0] * dd); o.y = f2bf_rne(acc[i][1] * dd);
                o.z = f2bf_rne(acc[i][2] * dd); o.w = f2bf_rne(acc[i][3] * dd);
                *(ushort4*)&Y[(size_t)r * 64 + c] = o;
            }
        }
    }
}

// ---------------- Aggregate (R18): 2 nodes/wave, interleaved chains --------
// xw: bf16 rows, stride 64 elems (128B), dinv-prescaled. Wave w owns nodes
// 2w (A) and 2w+1 (B). Per 8-edge step: {off,w} via 2 ds_bpermute, one
// global_load_dwordx4 covers 8 rows (8 lanes x 16B). A/B steps interleave
// (independent register chains). Epilogue: lanes 0-7 store A, 8-15 store B.
template <int FOUT, bool RELU>
__global__ __launch_bounds__(256) void agg_kernel(
        const unsigned short* __restrict__ xw,
        const int2* __restrict__ csr, const int* __restrict__ row_start,
        const int* __restrict__ row_cnt, const float* __restrict__ dinv,
        const float* __restrict__ bias, float* __restrict__ out, int N) {
    int w = (int)((blockIdx.x * blockDim.x + threadIdx.x) >> 6);
    int lane = threadIdx.x & 63;
    const int nA = 2 * w;
    const int nB = 2 * w + 1;
    if (nA >= N) return;
    const bool hasB = (nB < N);

    const int2* rowA = csr + row_start[nA];
    const int   cntA = row_cnt[nA];
    const int2* rowB = hasB ? (csr + row_start[nB]) : rowA;
    const int   cntB = hasB ? row_cnt[nB] : 0;
    const char* xwb = (const char*)xw;

    const int g = lane >> 3;                           // edge slot in step
    const unsigned li16 = (unsigned)(lane & 7) * 16u;  // byte chunk in row
    const int g4 = g << 2;                             // bpermute byte base

    float accA[8] = {0.f, 0.f, 0.f, 0.f, 0.f, 0.f, 0.f, 0.f};
    float accB[8] = {0.f, 0.f, 0.f, 0.f, 0.f, 0.f, 0.f, 0.f};

    // prime block 0 for both chains
    int2 eA = make_int2(0, 0), eB = make_int2(0, 0);
    if (lane < cntA) eA = rowA[lane];
    if (lane < cntB) eB = rowB[lane];

    const int cmax = max(cntA, cntB);
    for (int base = 0; base < cmax; base += 64) {
        const int mA = min(max(cntA - base, 0), 64);
        const int mB = min(max(cntB - base, 0), 64);
        // prefetch next blocks (overlap with processing)
        int2 enA = make_int2(0, 0), enB = make_int2(0, 0);
        const int nb = base + 64;
        if (nb < cntA) { if (lane < cntA - nb) enA = rowA[nb + lane]; }
        if (nb < cntB) { if (lane < cntB - nb) enB = rowB[nb + lane]; }
        int bidx = g4;
        #pragma unroll 2
        for (int t = 0; t * 8 < cmax - base && t < 8; ++t, bidx += 32) {
            if (t * 8 < mA) {
                unsigned off = (unsigned)__builtin_amdgcn_ds_bpermute(bidx, eA.x);
                unsigned wu  = (unsigned)__builtin_amdgcn_ds_bpermute(bidx, eA.y);
                const bool valid = (t * 8 + g) < mA;
                off = valid ? off : 0u;
                float wf = valid ? __uint_as_float(wu) : 0.f;
                uint4 rv = *(const uint4*)(xwb + (size_t)(off + li16));
                accA[0] = fmaf(wf, bflo(rv.x), accA[0]);
                accA[1] = fmaf(wf, bfhi(rv.x), accA[1]);
                accA[2] = fmaf(wf, bflo(rv.y), accA[2]);
                accA[3] = fmaf(wf, bfhi(rv.y), accA[3]);
                accA[4] = fmaf(wf, bflo(rv.z), accA[4]);
                accA[5] = fmaf(wf, bfhi(rv.z), accA[5]);
                accA[6] = fmaf(wf, bflo(rv.w), accA[6]);
                accA[7] = fmaf(wf, bfhi(rv.w), accA[7]);
            }
            if (t * 8 < mB) {
                unsigned off = (unsigned)__builtin_amdgcn_ds_bpermute(bidx, eB.x);
                unsigned wu  = (unsigned)__builtin_amdgcn_ds_bpermute(bidx, eB.y);
                const bool valid = (t * 8 + g) < mB;
                off = valid ? off : 0u;
                float wf = valid ? __uint_as_float(wu) : 0.f;
                uint4 rv = *(const uint4*)(xwb + (size_t)(off + li16));
                accB[0] = fmaf(wf, bflo(rv.x), accB[0]);
                accB[1] = fmaf(wf, bfhi(rv.x), accB[1]);
                accB[2] = fmaf(wf, bflo(rv.y), accB[2]);
                accB[3] = fmaf(wf, bfhi(rv.y), accB[3]);
                accB[4] = fmaf(wf, bflo(rv.z), accB[4]);
                accB[5] = fmaf(wf, bfhi(rv.z), accB[5]);
                accB[6] = fmaf(wf, bflo(rv.w), accB[6]);
                accB[7] = fmaf(wf, bfhi(rv.w), accB[7]);
            }
        }
        eA = enA; eB = enB;
    }

    // reduce both chains across the 8 edge groups
    #pragma unroll
    for (int o = 8; o <= 32; o <<= 1) {
        #pragma unroll
        for (int t = 0; t < 8; ++t) {
            accA[t] += __shfl_xor(accA[t], o);
            accB[t] += __shfl_xor(accB[t], o);
        }
    }

    // epilogue: lanes 0-7 store node A, lanes 8-15 store node B
    const int role = lane >> 3;          // 0 = A-writer, 1 = B-writer
    const int f0 = (lane & 7) * 8;
    if (lane < 16 && f0 < FOUT && (role == 0 || hasB)) {
        const int node = role ? nB : nA;
        float* accp = role ? accB : accA;
        uint4 sr = *(const uint4*)(xwb + (size_t)node * 128u + (unsigned)(lane & 7) * 16u);
        float dd = dinv[node];
        float4 bv0 = *(const float4*)&bias[f0];
        float4 bv1 = *(const float4*)&bias[f0 + 4];
        float r0 = dd * (accp[0] + bflo(sr.x)) + bv0.x;
        float r1 = dd * (accp[1] + bfhi(sr.x)) + bv0.y;
        float r2 = dd * (accp[2] + bflo(sr.y)) + bv0.z;
        float r3 = dd * (accp[3] + bfhi(sr.y)) + bv0.w;
        float r4 = dd * (accp[4] + bflo(sr.z)) + bv1.x;
        float r5 = dd * (accp[5] + bfhi(sr.z)) + bv1.y;
        float r6 = dd * (accp[6] + bflo(sr.w)) + bv1.z;
        float r7 = dd * (accp[7] + bfhi(sr.w)) + bv1.w;
        if (RELU) {
            r0 = fmaxf(r0, 0.f); r1 = fmaxf(r1, 0.f); r2 = fmaxf(r2, 0.f); r3 = fmaxf(r3, 0.f);
            r4 = fmaxf(r4, 0.f); r5 = fmaxf(r5, 0.f); r6 = fmaxf(r6, 0.f); r7 = fmaxf(r7, 0.f);
        }
        *(float4*)&out[(size_t)node * FOUT + f0]     = make_float4(r0, r1, r2, r3);
        *(float4*)&out[(size_t)node * FOUT + f0 + 4] = make_float4(r4, r5, r6, r7);
    }
}

static inline size_t ws_align(size_t x) { return (x + 255) & ~(size_t)255; }

extern "C" void kernel_launch(void* const* d_in, const int* in_sizes, int n_in,
                              void* d_out, int out_size, void* d_ws, size_t ws_size,
                              hipStream_t stream) {
    const float* x  = (const float*)d_in[0];
    const int*   ei = (const int*)d_in[1];
    const float* ew = (const float*)d_in[2];
    const float* W1 = (const float*)d_in[3];
    const float* b1 = (const float*)d_in[4];
    const float* W2 = (const float*)d_in[5];
    const float* b2 = (const float*)d_in[6];
    const float* W3 = (const float*)d_in[7];
    const float* b3 = (const float*)d_in[8];
    float* out = (float*)d_out;

    const int N = in_sizes[0] / 128;   // 50000
    const int E = in_sizes[1] / 2;     // 1600000
    const int* src = ei;
    const int* dst = ei + E;
    const int nbins = (N + 255) >> 8;         // 196
    const int ntiles = (E + TILE - 1) / TILE; // 391 (must be <= 512 for scan)

    char* p = (char*)d_ws;
    size_t off = 0;
    auto alloc = [&](size_t bytes) -> char* {
        char* q = p + off;
        off = ws_align(off + bytes);
        return q;
    };
    int*   row_start = (int*)  alloc((size_t)N * 4);
    int*   row_cnt   = (int*)  alloc((size_t)N * 4);
    float* dinv      = (float*)alloc((size_t)N * 4);
    int*   cntbase   = (int*)  alloc((size_t)256 * ntiles * 4);  // [bin][tile]
    int*   bintotal  = (int*)  alloc((size_t)256 * 4);
    unsigned short* xwbuf = (unsigned short*)alloc((size_t)N * 64 * 2);  // bf16, stride 64
    float* hbuf      = (float*)alloc((size_t)N * 64 * 4);                // fp32 h
    size_t remain = (ws_size > off) ? (ws_size - off) : 0;
    int bcap = (int)(remain / ((size_t)nbins * 8));
    if (bcap > BCAP_MAX) bcap = BCAP_MAX;
    int2* binned = (int2*)alloc((size_t)nbins * (size_t)bcap * 8);

    const int gb = (N + 63) / 64;           // 782 GEMM tiles
    const int ab = ((N + 1) / 2 * 64 + 255) / 256;   // one wave per 2 nodes

    bin_count_kernel<<<ntiles, 1024, 0, stream>>>(dst, cntbase, E, ntiles);
    bin_scan_kernel<<<256, 512, 0, stream>>>(cntbase, bintotal, ntiles);
    bin_scatter_kernel<<<ntiles, 1024, 0, stream>>>(src, dst, ew, cntbase, binned, E, bcap, ntiles);
    bin_group_kernel<<<nbins, 1024, 0, stream>>>(binned, bintotal, row_start, row_cnt, dinv, N, bcap);

    gemm_kernel<128, 64><<<gb, 256, 0, stream>>>(x, W1, dinv, xwbuf, N);
    agg_kernel<64, true ><<<ab, 256, 0, stream>>>(xwbuf, binned, row_start, row_cnt, dinv, b1, hbuf, N);
    gemm_kernel<64, 64><<<gb, 256, 0, stream>>>(hbuf, W2, dinv, xwbuf, N);
    agg_kernel<64, true ><<<ab, 256, 0, stream>>>(xwbuf, binned, row_start, row_cnt, dinv, b2, hbuf, N);
    gemm_kernel<64, 40><<<gb, 256, 0, stream>>>(hbuf, W3, dinv, xwbuf, N);
    agg_kernel<40, false><<<ab, 256, 0, stream>>>(xwbuf, binned, row_start, row_cnt, dinv, b3, out, N);
}